// Round 1
// baseline (924.250 us; speedup 1.0000x reference)
//
#include <hip/hip_runtime.h>
#include <hip/hip_bf16.h>
#include <math.h>

#define B 16
#define NN 50
#define D 400
#define H 20
#define DH 20
#define ATT_H 128
#define NEWS 20000
#define K 10
#define STEPS 6
#define SLOTS 10
#define L 500
#define EPS 1e-5f

// -------------------- Kernel 1: graph traversal --------------------
// One 256-thread block per (b,n). Wave w computes dot-products for k = w, w+4, w+8.
// Selection logic is wave-uniform (computed redundantly on every thread from LDS scores).
__global__ __launch_bounds__(256) void k_traverse(
    const float* __restrict__ news,   // [B,NN,D]
    const float* __restrict__ table,  // [NEWS,K,D]
    const int*   __restrict__ click,  // [B,NN]
    const int*   __restrict__ nbrt,   // [NEWS+1,K]
    float* __restrict__ x)            // [B,L,D]
{
    __shared__ float ssc[K];

    int item = blockIdx.x;            // 0..799
    int b = item / NN, n = item % NN;
    int tid = threadIdx.x;
    int lane = tid & 63, w = tid >> 6;

    // each lane loads a strided copy of the news vector (covers all 400 per wave)
    float nv[7];
    bool nzf = false;
    #pragma unroll
    for (int i = 0; i < 7; i++) {
        int d = lane + 64 * i;
        float v = (d < D) ? news[(size_t)item * D + d] : 0.0f;
        nv[i] = v;
        nzf |= (v != 0.0f);
    }
    float valid = __any(nzf) ? 1.0f : 0.0f;

    int idx = click[item];
    bool dead = false;
    float* xbase = x + ((size_t)b * L + (size_t)n * SLOTS) * D;

    for (int step = 0; step < STEPS; step++) {
        const float* tb = table + (size_t)(idx - 1) * K * D;
        for (int kk = w; kk < K; kk += 4) {
            float p = 0.0f;
            #pragma unroll
            for (int i = 0; i < 7; i++) {
                int d = lane + 64 * i;
                if (d < D) p += tb[kk * D + d] * nv[i];
            }
            #pragma unroll
            for (int off = 32; off > 0; off >>= 1) p += __shfl_xor(p, off);
            if (lane == 0) ssc[kk] = p;
        }
        __syncthreads();

        float scores[K];
        #pragma unroll
        for (int kk = 0; kk < K; kk++) scores[kk] = ssc[kk];

        // first-occurrence argmax (jnp.argmax semantics)
        int mx_i = 0; float mx_v = scores[0];
        #pragma unroll
        for (int kk = 1; kk < K; kk++)
            if (scores[kk] > mx_v) { mx_v = scores[kk]; mx_i = kk; }

        bool any_nz = false; int nz_i = 0; float nz_v = -INFINITY;
        #pragma unroll
        for (int kk = 0; kk < K; kk++) {
            if (scores[kk] != 0.0f) {
                if (!any_nz || scores[kk] > nz_v) { nz_v = scores[kk]; nz_i = kk; }
                any_nz = true;
            }
        }

        bool hop = (mx_v == 0.0f) && !dead;
        int sel_i = (hop && any_nz) ? nz_i : mx_i;
        bool new_dead = dead || (hop && !any_nz);
        int nbr = nbrt[(size_t)idx * K + sel_i];   // neighbor_table[idx] (not idx-1)
        int new_idx = (hop && any_nz) ? nbr : idx;

        float scale = new_dead ? 0.0f : valid;
        const float* selrow = tb + (size_t)sel_i * D;
        float* xr = xbase + (size_t)step * D;
        for (int d = tid; d < D; d += 256) xr[d] = selrow[d] * scale;

        idx = new_idx; dead = new_dead;
        __syncthreads();   // protect ssc for next step
    }
    // zero-pad slots 6..9 (ws is poisoned every call)
    for (int s = STEPS; s < SLOTS; s++) {
        float* xr = xbase + (size_t)s * D;
        for (int d = tid; d < D; d += 256) xr[d] = 0.0f;
    }
}

// -------------------- Kernel 2: QKV projection GEMM --------------------
// C[8000,400] = x[8000,400] @ W[400,400], z selects Wq/Wk/Wv.
// Tile 64x80, k-tile 16, each thread 4 rows x 5 cols. Output in [B,H,L,DH].
#define TM 64
#define TN 80
#define TKK 16

__global__ __launch_bounds__(256) void k_qkv(
    const float* __restrict__ x,
    const float* __restrict__ Wq, const float* __restrict__ Wk, const float* __restrict__ Wv,
    float* __restrict__ qb, float* __restrict__ kb, float* __restrict__ vb)
{
    const float* W = (blockIdx.z == 0) ? Wq : (blockIdx.z == 1) ? Wk : Wv;
    float* out     = (blockIdx.z == 0) ? qb : (blockIdx.z == 1) ? kb : vb;

    __shared__ float As[TM][TKK + 1];
    __shared__ float Bs[TKK][TN];

    int tid = threadIdx.x;
    int cx = tid & 15, ry = tid >> 4;
    int rm0 = blockIdx.x * TM;
    int cn0 = blockIdx.y * TN;

    float acc[4][5];
    #pragma unroll
    for (int i = 0; i < 4; i++)
        #pragma unroll
        for (int j = 0; j < 5; j++) acc[i][j] = 0.0f;

    for (int k0 = 0; k0 < D; k0 += TKK) {
        #pragma unroll
        for (int t = tid; t < TM * TKK; t += 256) {
            int r = t >> 4, k = t & 15;
            As[r][k] = x[(size_t)(rm0 + r) * D + k0 + k];
        }
        #pragma unroll
        for (int t = tid; t < TKK * TN; t += 256) {
            int k = t / TN, c = t % TN;
            Bs[k][c] = W[(size_t)(k0 + k) * D + cn0 + c];
        }
        __syncthreads();
        #pragma unroll
        for (int k = 0; k < TKK; k++) {
            float a0 = As[ry * 4 + 0][k], a1 = As[ry * 4 + 1][k];
            float a2 = As[ry * 4 + 2][k], a3 = As[ry * 4 + 3][k];
            float bb[5];
            #pragma unroll
            for (int j = 0; j < 5; j++) bb[j] = Bs[k][cx + 16 * j];
            #pragma unroll
            for (int j = 0; j < 5; j++) {
                acc[0][j] += a0 * bb[j];
                acc[1][j] += a1 * bb[j];
                acc[2][j] += a2 * bb[j];
                acc[3][j] += a3 * bb[j];
            }
        }
        __syncthreads();
    }
    #pragma unroll
    for (int i = 0; i < 4; i++) {
        int gr = rm0 + ry * 4 + i;
        int bb2 = gr / L, ll = gr % L;
        #pragma unroll
        for (int j = 0; j < 5; j++) {
            int gc = cn0 + cx + 16 * j;
            int h = gc / DH, dh = gc % DH;
            out[(((size_t)bb2 * H + h) * L + ll) * DH + dh] = acc[i][j];
        }
    }
}

// -------------------- Kernel 3: attention --------------------
// One block per (b,h). K/V staged in LDS in 250-row tiles; online softmax.
// Each thread owns q-rows l = tid and tid+256. j-loop is wave-uniform -> LDS broadcasts.
#define JT 250

__global__ __launch_bounds__(256) void k_attn(
    const float* __restrict__ qg, const float* __restrict__ kg, const float* __restrict__ vg,
    const int* __restrict__ mask,  // [B,L]
    float* __restrict__ o)         // [B,L,H*DH]
{
    __shared__ float Ksh[JT * DH];
    __shared__ float Vsh[JT * DH];
    __shared__ float msk[L];

    int b = blockIdx.x / H, h = blockIdx.x % H;
    int tid = threadIdx.x;

    const float* kp = kg + (((size_t)b * H + h) * L) * DH;
    const float* vp = vg + (((size_t)b * H + h) * L) * DH;
    for (int i = tid; i < L; i += 256)
        msk[i] = (mask[(size_t)b * L + i] > 0) ? 1.0f : 0.0f;

    const float scale = 0.22360679774997896f;  // 1/sqrt(20)
    int l0 = tid;
    int l1 = tid + 256;
    bool has1 = (l1 < L);

    float q0[DH], q1[DH];
    const float* qp0 = qg + (((size_t)b * H + h) * L + l0) * DH;
    #pragma unroll
    for (int d = 0; d < DH; d++) q0[d] = qp0[d] * scale;
    if (has1) {
        const float* qp1 = qg + (((size_t)b * H + h) * L + l1) * DH;
        #pragma unroll
        for (int d = 0; d < DH; d++) q1[d] = qp1[d] * scale;
    }

    float m0 = -INFINITY, s0 = 0.0f, acc0[DH];
    float m1 = -INFINITY, s1 = 0.0f, acc1[DH];
    #pragma unroll
    for (int d = 0; d < DH; d++) { acc0[d] = 0.0f; acc1[d] = 0.0f; }

    for (int j0 = 0; j0 < L; j0 += JT) {
        __syncthreads();
        for (int i = tid; i < JT * DH; i += 256) {
            Ksh[i] = kp[(size_t)j0 * DH + i];
            Vsh[i] = vp[(size_t)j0 * DH + i];
        }
        __syncthreads();
        #pragma unroll 1
        for (int jj = 0; jj < JT; jj++) {
            float kr[DH], vr[DH];
            #pragma unroll
            for (int d = 0; d < DH; d++) kr[d] = Ksh[jj * DH + d];
            #pragma unroll
            for (int d = 0; d < DH; d++) vr[d] = Vsh[jj * DH + d];
            float mk = msk[j0 + jj];

            float sc = 0.0f;
            #pragma unroll
            for (int d = 0; d < DH; d++) sc += q0[d] * kr[d];
            sc = (mk > 0.5f) ? sc : -1e9f;
            if (sc > m0) {
                float r = __expf(m0 - sc);
                s0 *= r;
                #pragma unroll
                for (int d = 0; d < DH; d++) acc0[d] *= r;
                m0 = sc;
            }
            float e0 = __expf(sc - m0);
            s0 += e0;
            #pragma unroll
            for (int d = 0; d < DH; d++) acc0[d] += e0 * vr[d];

            if (has1) {
                float sc1 = 0.0f;
                #pragma unroll
                for (int d = 0; d < DH; d++) sc1 += q1[d] * kr[d];
                sc1 = (mk > 0.5f) ? sc1 : -1e9f;
                if (sc1 > m1) {
                    float r = __expf(m1 - sc1);
                    s1 *= r;
                    #pragma unroll
                    for (int d = 0; d < DH; d++) acc1[d] *= r;
                    m1 = sc1;
                }
                float e1 = __expf(sc1 - m1);
                s1 += e1;
                #pragma unroll
                for (int d = 0; d < DH; d++) acc1[d] += e1 * vr[d];
            }
        }
    }

    float inv0 = 1.0f / s0;
    float* op0 = o + ((size_t)b * L + l0) * (H * DH) + h * DH;
    #pragma unroll
    for (int d = 0; d < DH; d++) op0[d] = acc0[d] * inv0;
    if (has1) {
        float inv1 = 1.0f / s1;
        float* op1 = o + ((size_t)b * L + l1) * (H * DH) + h * DH;
        #pragma unroll
        for (int d = 0; d < DH; d++) op1[d] = acc1[d] * inv1;
    }
}

// -------------------- Kernel 4: LN1 + att_pool + LN2 --------------------
// One block per (b,n) group of 10 slots.
__global__ __launch_bounds__(256) void k_pool(
    const float* __restrict__ o,
    const float* __restrict__ ln1g, const float* __restrict__ ln1b,
    const float* __restrict__ fc1w, const float* __restrict__ fc1b,
    const float* __restrict__ fc2w, const float* __restrict__ fc2b,
    const float* __restrict__ ln2g, const float* __restrict__ ln2b,
    const int* __restrict__ mask,   // viewed as [800,10]
    float* __restrict__ out)        // [800,400]
{
    __shared__ float xt[SLOTS][D];
    __shared__ float hv[SLOTS * ATT_H];
    __shared__ float es[SLOTS];
    __shared__ float red[8];

    int g = blockIdx.x;
    int tid = threadIdx.x;
    int lane = tid & 63, w = tid >> 6;

    const float* xg = o + (size_t)g * SLOTS * D;

    // LN1 per slot row: wave w handles rows w, w+4, w+8
    for (int s = w; s < SLOTS; s += 4) {
        const float* xr = xg + (size_t)s * D;
        float vbuf[7];
        float sum = 0.0f, sq = 0.0f;
        #pragma unroll
        for (int i = 0; i < 7; i++) {
            int d = lane + 64 * i;
            float v = (d < D) ? xr[d] : 0.0f;
            vbuf[i] = v; sum += v; sq += v * v;
        }
        #pragma unroll
        for (int off = 32; off > 0; off >>= 1) {
            sum += __shfl_xor(sum, off);
            sq  += __shfl_xor(sq, off);
        }
        float mean = sum / (float)D;
        float var = sq / (float)D - mean * mean;
        float rs = rsqrtf(var + EPS);
        #pragma unroll
        for (int i = 0; i < 7; i++) {
            int d = lane + 64 * i;
            if (d < D) xt[s][d] = (vbuf[i] - mean) * rs * ln1g[d] + ln1b[d];
        }
    }
    __syncthreads();

    // hidden = tanh(xt @ fc1 + b1) * fc2w ; each thread: fixed jh, 5 slots sharing weight loads
    {
        int jh = tid & 127;
        int s0 = tid >> 7;   // 0 or 1
        float hs[5];
        #pragma unroll
        for (int jj = 0; jj < 5; jj++) hs[jj] = fc1b[jh];
        for (int d = 0; d < D; d++) {
            float fw = fc1w[(size_t)d * ATT_H + jh];
            #pragma unroll
            for (int jj = 0; jj < 5; jj++) hs[jj] += xt[s0 + 2 * jj][d] * fw;
        }
        float f2 = fc2w[jh];
        #pragma unroll
        for (int jj = 0; jj < 5; jj++)
            hv[(s0 + 2 * jj) * ATT_H + jh] = tanhf(hs[jj]) * f2;
    }
    __syncthreads();

    // reduce 128 -> e[s]
    for (int s = w; s < SLOTS; s += 4) {
        float p = hv[s * ATT_H + lane] + hv[s * ATT_H + lane + 64];
        #pragma unroll
        for (int off = 32; off > 0; off >>= 1) p += __shfl_xor(p, off);
        if (lane == 0) es[s] = p + fc2b[0];
    }
    __syncthreads();

    // slot softmax (uniform per thread)
    float ev[SLOTS];
    float emax = -INFINITY;
    #pragma unroll
    for (int s = 0; s < SLOTS; s++) {
        float e = (mask[(size_t)g * SLOTS + s] > 0) ? es[s] : -1e9f;
        ev[s] = e;
        if (e > emax) emax = e;
    }
    float esum = 0.0f;
    #pragma unroll
    for (int s = 0; s < SLOTS; s++) { ev[s] = __expf(ev[s] - emax); esum += ev[s]; }
    float einv = 1.0f / esum;

    // pooled + LN2
    int d0 = tid, d1 = tid + 256;
    float p0 = 0.0f, p1 = 0.0f;
    #pragma unroll
    for (int s = 0; s < SLOTS; s++) {
        p0 += ev[s] * xt[s][d0];
        if (d1 < D) p1 += ev[s] * xt[s][d1];
    }
    p0 *= einv; p1 *= einv;

    float sum = p0 + ((d1 < D) ? p1 : 0.0f);
    float sq  = p0 * p0 + ((d1 < D) ? p1 * p1 : 0.0f);
    #pragma unroll
    for (int off = 32; off > 0; off >>= 1) {
        sum += __shfl_xor(sum, off);
        sq  += __shfl_xor(sq, off);
    }
    if (lane == 0) { red[w] = sum; red[4 + w] = sq; }
    __syncthreads();
    float tsum = red[0] + red[1] + red[2] + red[3];
    float tsq  = red[4] + red[5] + red[6] + red[7];
    float mean = tsum / (float)D;
    float var = tsq / (float)D - mean * mean;
    float rs = rsqrtf(var + EPS);

    float* og = out + (size_t)g * D;
    og[d0] = (p0 - mean) * rs * ln2g[d0] + ln2b[d0];
    if (d1 < D) og[d1] = (p1 - mean) * rs * ln2g[d1] + ln2b[d1];
}

extern "C" void kernel_launch(void* const* d_in, const int* in_sizes, int n_in,
                              void* d_out, int out_size, void* d_ws, size_t ws_size,
                              hipStream_t stream) {
    const float* news  = (const float*)d_in[0];
    const float* table = (const float*)d_in[1];
    const float* Wq    = (const float*)d_in[2];
    const float* Wk    = (const float*)d_in[3];
    const float* Wv    = (const float*)d_in[4];
    const float* ln1g  = (const float*)d_in[5];
    const float* ln1b  = (const float*)d_in[6];
    const float* fc1w  = (const float*)d_in[7];
    const float* fc1b  = (const float*)d_in[8];
    const float* fc2w  = (const float*)d_in[9];
    const float* fc2b  = (const float*)d_in[10];
    const float* ln2g  = (const float*)d_in[11];
    const float* ln2b  = (const float*)d_in[12];
    const int* click   = (const int*)d_in[13];
    const int* nbrt    = (const int*)d_in[14];
    const int* mask    = (const int*)d_in[15];
    float* out = (float*)d_out;

    float* ws = (float*)d_ws;
    const size_t NX = (size_t)B * L * D;   // 3.2M floats
    float* x  = ws;
    float* qb = ws + NX;
    float* kb = ws + 2 * NX;
    float* vb = ws + 3 * NX;
    float* ob = ws + 4 * NX;

    k_traverse<<<dim3(B * NN), dim3(256), 0, stream>>>(news, table, click, nbrt, x);
    k_qkv<<<dim3((B * L) / TM, D / TN, 3), dim3(256), 0, stream>>>(x, Wq, Wk, Wv, qb, kb, vb);
    k_attn<<<dim3(B * H), dim3(256), 0, stream>>>(qb, kb, vb, mask, ob);
    k_pool<<<dim3(B * NN), dim3(256), 0, stream>>>(ob, ln1g, ln1b, fc1w, fc1b, fc2w, fc2b,
                                                   ln2g, ln2b, mask, out);
}

// Round 2
// 787.616 us; speedup vs baseline: 1.1735x; 1.1735x over previous
//
#include <hip/hip_runtime.h>
#include <hip/hip_bf16.h>
#include <math.h>

#define B 16
#define NN 50
#define D 400
#define H 20
#define DH 20
#define ATT_H 128
#define NEWS 20000
#define K 10
#define STEPS 6
#define SLOTS 10
#define L 500
#define EPS 1e-5f

#define XP 416            // padded K-dim (13 * 32), bf16 row stride for x and wT
#define NC 1200           // q|k|v concatenated N

typedef short short8 __attribute__((ext_vector_type(8)));
typedef float floatx4 __attribute__((ext_vector_type(4)));

__device__ __forceinline__ short f2bf(float f) {
    __hip_bfloat16 h = __float2bfloat16(f);
    return *reinterpret_cast<short*>(&h);
}

// -------------------- Kernel 1: graph traversal (emits x in bf16, padded) ----
__global__ __launch_bounds__(256) void k_traverse(
    const float* __restrict__ news,   // [B,NN,D]
    const float* __restrict__ table,  // [NEWS,K,D]
    const int*   __restrict__ click,  // [B,NN]
    const int*   __restrict__ nbrt,   // [NEWS+1,K]
    short* __restrict__ x)            // [B*L][XP] bf16
{
    __shared__ float ssc[K];

    int item = blockIdx.x;            // 0..799
    int b = item / NN, n = item % NN;
    int tid = threadIdx.x;
    int lane = tid & 63, w = tid >> 6;

    float nv[7];
    bool nzf = false;
    #pragma unroll
    for (int i = 0; i < 7; i++) {
        int d = lane + 64 * i;
        float v = (d < D) ? news[(size_t)item * D + d] : 0.0f;
        nv[i] = v;
        nzf |= (v != 0.0f);
    }
    float valid = __any(nzf) ? 1.0f : 0.0f;

    int idx = click[item];
    bool dead = false;
    short* xbase = x + (size_t)(b * L + n * SLOTS) * XP;

    for (int step = 0; step < STEPS; step++) {
        const float* tb = table + (size_t)(idx - 1) * K * D;
        for (int kk = w; kk < K; kk += 4) {
            float p = 0.0f;
            #pragma unroll
            for (int i = 0; i < 7; i++) {
                int d = lane + 64 * i;
                if (d < D) p += tb[kk * D + d] * nv[i];
            }
            #pragma unroll
            for (int off = 32; off > 0; off >>= 1) p += __shfl_xor(p, off);
            if (lane == 0) ssc[kk] = p;
        }
        __syncthreads();

        float scores[K];
        #pragma unroll
        for (int kk = 0; kk < K; kk++) scores[kk] = ssc[kk];

        int mx_i = 0; float mx_v = scores[0];
        #pragma unroll
        for (int kk = 1; kk < K; kk++)
            if (scores[kk] > mx_v) { mx_v = scores[kk]; mx_i = kk; }

        bool any_nz = false; int nz_i = 0; float nz_v = -INFINITY;
        #pragma unroll
        for (int kk = 0; kk < K; kk++) {
            if (scores[kk] != 0.0f) {
                if (!any_nz || scores[kk] > nz_v) { nz_v = scores[kk]; nz_i = kk; }
                any_nz = true;
            }
        }

        bool hop = (mx_v == 0.0f) && !dead;
        int sel_i = (hop && any_nz) ? nz_i : mx_i;
        bool new_dead = dead || (hop && !any_nz);
        int nbr = nbrt[(size_t)idx * K + sel_i];
        int new_idx = (hop && any_nz) ? nbr : idx;

        float scale = new_dead ? 0.0f : valid;
        const float* selrow = tb + (size_t)sel_i * D;
        short* xr = xbase + (size_t)step * XP;
        for (int d = tid; d < XP; d += 256)
            xr[d] = (d < D) ? f2bf(selrow[d] * scale) : (short)0;

        idx = new_idx; dead = new_dead;
        __syncthreads();
    }
    for (int s = STEPS; s < SLOTS; s++) {
        short* xr = xbase + (size_t)s * XP;
        for (int d = tid; d < XP; d += 256) xr[d] = 0;
    }
}

// -------------------- Kernel 1b: weight transpose+concat to bf16 -------------
// wT[c][k] = W_{c/400}[k][c%400], zero-padded k in [400,416)
__global__ __launch_bounds__(256) void k_wconvT(
    const float* __restrict__ Wq, const float* __restrict__ Wk,
    const float* __restrict__ Wv, short* __restrict__ wT)
{
    int c = blockIdx.x;               // 0..1199
    int z = c / 400, n = c % 400;
    const float* W = (z == 0) ? Wq : (z == 1) ? Wk : Wv;
    for (int k = threadIdx.x; k < XP; k += 256)
        wT[(size_t)c * XP + k] = (k < 400) ? f2bf(W[(size_t)k * 400 + n]) : (short)0;
}

// -------------------- Kernel 2: fused QKV GEMM via bf16 MFMA ----------------
// C[8000,1200] = x[8000,416] @ wT^T ; tile 128x64, BK=32, 4 waves (2x2),
// each wave: 4x2 frags of mfma_f32_16x16x32_bf16.
#define BM 128
#define BN 64
#define BKK 32

__global__ __launch_bounds__(256) void k_qkv_mfma(
    const short* __restrict__ xg,      // [8000][XP] bf16
    const short* __restrict__ wT,      // [1200][XP] bf16
    float* __restrict__ c)             // [8000][1200]
{
    __shared__ short xs[BM][BKK + 8];  // +8 shorts pad: 20-bank step, 2-way = free
    __shared__ short wt[BN][BKK + 8];

    int tid = threadIdx.x;
    int m0 = blockIdx.x * BM;
    int n0 = blockIdx.y * BN;
    int lane = tid & 63, w = tid >> 6;
    int wr = w >> 1, wc = w & 1;
    int quad = lane >> 4, l16 = lane & 15;

    floatx4 acc[4][2];
    #pragma unroll
    for (int i = 0; i < 4; i++)
        #pragma unroll
        for (int j = 0; j < 2; j++) acc[i][j] = (floatx4){0.f, 0.f, 0.f, 0.f};

    int xr = tid >> 1, xc = (tid & 1) * 16;
    int wrow = tid >> 2, wcol8 = (tid & 3) * 8;
    bool xok = (m0 + xr) < 8000;
    bool wok = (n0 + wrow) < NC;

    for (int k0 = 0; k0 < XP; k0 += BKK) {
        int4 xv0 = {0,0,0,0}, xv1 = {0,0,0,0}, wv = {0,0,0,0};
        if (xok) {
            const int4* src = (const int4*)(xg + (size_t)(m0 + xr) * XP + k0 + xc);
            xv0 = src[0]; xv1 = src[1];
        }
        if (wok)
            wv = *(const int4*)(wT + (size_t)(n0 + wrow) * XP + k0 + wcol8);
        __syncthreads();
        *(int4*)&xs[xr][xc]      = xv0;
        *(int4*)&xs[xr][xc + 8]  = xv1;
        *(int4*)&wt[wrow][wcol8] = wv;
        __syncthreads();

        short8 a[4], bf[2];
        #pragma unroll
        for (int fi = 0; fi < 4; fi++)
            a[fi] = *(const short8*)&xs[wr * 64 + fi * 16 + l16][quad * 8];
        #pragma unroll
        for (int fj = 0; fj < 2; fj++)
            bf[fj] = *(const short8*)&wt[wc * 32 + fj * 16 + l16][quad * 8];
        #pragma unroll
        for (int fi = 0; fi < 4; fi++)
            #pragma unroll
            for (int fj = 0; fj < 2; fj++)
                acc[fi][fj] = __builtin_amdgcn_mfma_f32_16x16x32_bf16(
                    a[fi], bf[fj], acc[fi][fj], 0, 0, 0);
    }

    #pragma unroll
    for (int fi = 0; fi < 4; fi++) {
        int grow_base = m0 + wr * 64 + fi * 16 + quad * 4;
        #pragma unroll
        for (int fj = 0; fj < 2; fj++) {
            int gcol = n0 + wc * 32 + fj * 16 + l16;
            #pragma unroll
            for (int r = 0; r < 4; r++) {
                int grow = grow_base + r;
                if (grow < 8000 && gcol < NC)
                    c[(size_t)grow * NC + gcol] = acc[fi][fj][r];
            }
        }
    }
}

// -------------------- Kernel 3: attention, two-pass softmax ------------------
// One block of 512 per (b,h); thread owns one q-row. K resident in LDS (fp32),
// V in two 250-row tiles. Pass1: row max. Pass2: exp + accumulate.
__global__ __launch_bounds__(512) void k_attn2(
    const float* __restrict__ qkv,   // [8000][1200] = q|k|v
    const int* __restrict__ mask,    // [B,L]
    float* __restrict__ o)           // [8000][400]
{
    __shared__ float Ksh[L][DH];      // 40000 B
    __shared__ float Vsh[250][DH];    // 20000 B
    __shared__ float msk[L];          // 2000 B

    int b = blockIdx.x / H, h = blockIdx.x % H;
    int tid = threadIdx.x;
    const float scale = 0.22360679774997896f;  // 1/sqrt(20)

    for (int i = tid; i < L; i += 512)
        msk[i] = (mask[(size_t)b * L + i] > 0) ? 1.0f : 0.0f;
    for (int i = tid; i < L * DH; i += 512) {
        int j = i / DH, d = i % DH;
        Ksh[j][d] = qkv[(size_t)(b * L + j) * NC + 400 + h * DH + d];
    }
    __syncthreads();

    bool live = tid < L;
    int l = live ? tid : 0;
    float q[DH];
    const float* qp = qkv + (size_t)(b * L + l) * NC + h * DH;
    #pragma unroll
    for (int d = 0; d < DH; d++) q[d] = qp[d] * scale;

    // pass 1: row max
    float m = -INFINITY;
    #pragma unroll 4
    for (int j = 0; j < L; j++) {
        float s0 = 0.f, s1 = 0.f, s2 = 0.f, s3 = 0.f;
        #pragma unroll
        for (int d = 0; d < DH; d += 4) {
            s0 += q[d]     * Ksh[j][d];
            s1 += q[d + 1] * Ksh[j][d + 1];
            s2 += q[d + 2] * Ksh[j][d + 2];
            s3 += q[d + 3] * Ksh[j][d + 3];
        }
        float sc = (s0 + s1) + (s2 + s3);
        sc = (msk[j] != 0.0f) ? sc : -1e9f;
        m = fmaxf(m, sc);
    }

    // pass 2: exp + accumulate (V tiled)
    float s = 0.0f, acc[DH];
    #pragma unroll
    for (int d = 0; d < DH; d++) acc[d] = 0.0f;

    for (int t = 0; t < 2; t++) {
        __syncthreads();
        for (int i = tid; i < 250 * DH; i += 512) {
            int j = i / DH, d = i % DH;
            Vsh[j][d] = qkv[(size_t)(b * L + t * 250 + j) * NC + 800 + h * DH + d];
        }
        __syncthreads();
        #pragma unroll 2
        for (int jj = 0; jj < 250; jj++) {
            int j = t * 250 + jj;
            float s0 = 0.f, s1 = 0.f, s2 = 0.f, s3 = 0.f;
            #pragma unroll
            for (int d = 0; d < DH; d += 4) {
                s0 += q[d]     * Ksh[j][d];
                s1 += q[d + 1] * Ksh[j][d + 1];
                s2 += q[d + 2] * Ksh[j][d + 2];
                s3 += q[d + 3] * Ksh[j][d + 3];
            }
            float sc = (s0 + s1) + (s2 + s3);
            sc = (msk[j] != 0.0f) ? sc : -1e9f;
            float e = __expf(sc - m);
            s += e;
            #pragma unroll
            for (int d = 0; d < DH; d++) acc[d] += e * Vsh[jj][d];
        }
    }

    if (live) {
        float inv = 1.0f / s;
        float* op = o + (size_t)(b * L + l) * (H * DH) + h * DH;
        #pragma unroll
        for (int d = 0; d < DH; d++) op[d] = acc[d] * inv;
    }
}

// -------------------- Kernel 4: LN1 + att_pool + LN2 ------------------------
__global__ __launch_bounds__(256) void k_pool(
    const float* __restrict__ o,
    const float* __restrict__ ln1g, const float* __restrict__ ln1b,
    const float* __restrict__ fc1w, const float* __restrict__ fc1b,
    const float* __restrict__ fc2w, const float* __restrict__ fc2b,
    const float* __restrict__ ln2g, const float* __restrict__ ln2b,
    const int* __restrict__ mask,   // [800,10]
    float* __restrict__ out)        // [800,400]
{
    __shared__ float xt[SLOTS][D];
    __shared__ float hv[SLOTS * ATT_H];
    __shared__ float es[SLOTS];
    __shared__ float red[8];

    int g = blockIdx.x;
    int tid = threadIdx.x;
    int lane = tid & 63, w = tid >> 6;

    const float* xg = o + (size_t)g * SLOTS * D;

    for (int s = w; s < SLOTS; s += 4) {
        const float* xr = xg + (size_t)s * D;
        float vbuf[7];
        float sum = 0.0f, sq = 0.0f;
        #pragma unroll
        for (int i = 0; i < 7; i++) {
            int d = lane + 64 * i;
            float v = (d < D) ? xr[d] : 0.0f;
            vbuf[i] = v; sum += v; sq += v * v;
        }
        #pragma unroll
        for (int off = 32; off > 0; off >>= 1) {
            sum += __shfl_xor(sum, off);
            sq  += __shfl_xor(sq, off);
        }
        float mean = sum / (float)D;
        float var = sq / (float)D - mean * mean;
        float rs = rsqrtf(var + EPS);
        #pragma unroll
        for (int i = 0; i < 7; i++) {
            int d = lane + 64 * i;
            if (d < D) xt[s][d] = (vbuf[i] - mean) * rs * ln1g[d] + ln1b[d];
        }
    }
    __syncthreads();

    {
        int jh = tid & 127;
        int s0 = tid >> 7;
        float hs[5];
        #pragma unroll
        for (int jj = 0; jj < 5; jj++) hs[jj] = fc1b[jh];
        for (int d = 0; d < D; d++) {
            float fw = fc1w[(size_t)d * ATT_H + jh];
            #pragma unroll
            for (int jj = 0; jj < 5; jj++) hs[jj] += xt[s0 + 2 * jj][d] * fw;
        }
        float f2 = fc2w[jh];
        #pragma unroll
        for (int jj = 0; jj < 5; jj++)
            hv[(s0 + 2 * jj) * ATT_H + jh] = tanhf(hs[jj]) * f2;
    }
    __syncthreads();

    for (int s = w; s < SLOTS; s += 4) {
        float p = hv[s * ATT_H + lane] + hv[s * ATT_H + lane + 64];
        #pragma unroll
        for (int off = 32; off > 0; off >>= 1) p += __shfl_xor(p, off);
        if (lane == 0) es[s] = p + fc2b[0];
    }
    __syncthreads();

    float ev[SLOTS];
    float emax = -INFINITY;
    #pragma unroll
    for (int s = 0; s < SLOTS; s++) {
        float e = (mask[(size_t)g * SLOTS + s] > 0) ? es[s] : -1e9f;
        ev[s] = e;
        if (e > emax) emax = e;
    }
    float esum = 0.0f;
    #pragma unroll
    for (int s = 0; s < SLOTS; s++) { ev[s] = __expf(ev[s] - emax); esum += ev[s]; }
    float einv = 1.0f / esum;

    int d0 = tid, d1 = tid + 256;
    float p0 = 0.0f, p1 = 0.0f;
    #pragma unroll
    for (int s = 0; s < SLOTS; s++) {
        p0 += ev[s] * xt[s][d0];
        if (d1 < D) p1 += ev[s] * xt[s][d1];
    }
    p0 *= einv; p1 *= einv;

    float sum = p0 + ((d1 < D) ? p1 : 0.0f);
    float sq  = p0 * p0 + ((d1 < D) ? p1 * p1 : 0.0f);
    #pragma unroll
    for (int off = 32; off > 0; off >>= 1) {
        sum += __shfl_xor(sum, off);
        sq  += __shfl_xor(sq, off);
    }
    if (lane == 0) { red[w] = sum; red[4 + w] = sq; }
    __syncthreads();
    float tsum = red[0] + red[1] + red[2] + red[3];
    float tsq  = red[4] + red[5] + red[6] + red[7];
    float mean = tsum / (float)D;
    float var = tsq / (float)D - mean * mean;
    float rs = rsqrtf(var + EPS);

    float* og = out + (size_t)g * D;
    og[d0] = (p0 - mean) * rs * ln2g[d0] + ln2b[d0];
    if (d1 < D) og[d1] = (p1 - mean) * rs * ln2g[d1] + ln2b[d1];
}

extern "C" void kernel_launch(void* const* d_in, const int* in_sizes, int n_in,
                              void* d_out, int out_size, void* d_ws, size_t ws_size,
                              hipStream_t stream) {
    const float* news  = (const float*)d_in[0];
    const float* table = (const float*)d_in[1];
    const float* Wq    = (const float*)d_in[2];
    const float* Wk    = (const float*)d_in[3];
    const float* Wv    = (const float*)d_in[4];
    const float* ln1g  = (const float*)d_in[5];
    const float* ln1b  = (const float*)d_in[6];
    const float* fc1w  = (const float*)d_in[7];
    const float* fc1b  = (const float*)d_in[8];
    const float* fc2w  = (const float*)d_in[9];
    const float* fc2b  = (const float*)d_in[10];
    const float* ln2g  = (const float*)d_in[11];
    const float* ln2b  = (const float*)d_in[12];
    const int* click   = (const int*)d_in[13];
    const int* nbrt    = (const int*)d_in[14];
    const int* mask    = (const int*)d_in[15];
    float* out = (float*)d_out;

    char* p = (char*)d_ws;
    short* xbf = (short*)p;  p += (size_t)8000 * XP * sizeof(short);   // 6.656 MB
    short* wT  = (short*)p;  p += (size_t)NC * XP * sizeof(short);     // 1.0 MB
    float* qkv = (float*)p;  p += (size_t)8000 * NC * sizeof(float);   // 38.4 MB
    float* ob  = (float*)p;                                            // 12.8 MB

    k_traverse<<<dim3(B * NN), dim3(256), 0, stream>>>(news, table, click, nbrt, xbf);
    k_wconvT<<<dim3(NC), dim3(256), 0, stream>>>(Wq, Wk, Wv, wT);
    k_qkv_mfma<<<dim3((8000 + BM - 1) / BM, (NC + BN - 1) / BN), dim3(256), 0, stream>>>(
        xbf, wT, qkv);
    k_attn2<<<dim3(B * H), dim3(512), 0, stream>>>(qkv, mask, ob);
    k_pool<<<dim3(B * NN), dim3(256), 0, stream>>>(ob, ln1g, ln1b, fc1w, fc1b, fc2w, fc2b,
                                                   ln2g, ln2b, mask, out);
}

// Round 3
// 624.361 us; speedup vs baseline: 1.4803x; 1.2615x over previous
//
#include <hip/hip_runtime.h>
#include <hip/hip_bf16.h>
#include <math.h>

#define B 16
#define NN 50
#define D 400
#define H 20
#define DH 20
#define ATT_H 128
#define NEWS 20000
#define K 10
#define STEPS 6
#define SLOTS 10
#define L 500
#define EPS 1e-5f

#define XP 416            // padded K-dim (13 * 32), bf16 row stride for x and wT
#define NC 1200           // q|k|v concatenated N

typedef short short8 __attribute__((ext_vector_type(8)));
typedef float floatx4 __attribute__((ext_vector_type(4)));

__device__ __forceinline__ short f2bf(float f) {
    __hip_bfloat16 h = __float2bfloat16(f);
    return *reinterpret_cast<short*>(&h);
}

// -------------------- Kernel 1: graph traversal (emits x in bf16, padded) ----
__global__ __launch_bounds__(256) void k_traverse(
    const float* __restrict__ news,   // [B,NN,D]
    const float* __restrict__ table,  // [NEWS,K,D]
    const int*   __restrict__ click,  // [B,NN]
    const int*   __restrict__ nbrt,   // [NEWS+1,K]
    short* __restrict__ x)            // [B*L][XP] bf16
{
    __shared__ float ssc[K];

    int item = blockIdx.x;            // 0..799
    int b = item / NN, n = item % NN;
    int tid = threadIdx.x;
    int lane = tid & 63, w = tid >> 6;

    float nv[7];
    bool nzf = false;
    #pragma unroll
    for (int i = 0; i < 7; i++) {
        int d = lane + 64 * i;
        float v = (d < D) ? news[(size_t)item * D + d] : 0.0f;
        nv[i] = v;
        nzf |= (v != 0.0f);
    }
    float valid = __any(nzf) ? 1.0f : 0.0f;

    int idx = click[item];
    bool dead = false;
    short* xbase = x + (size_t)(b * L + n * SLOTS) * XP;

    for (int step = 0; step < STEPS; step++) {
        const float* tb = table + (size_t)(idx - 1) * K * D;
        for (int kk = w; kk < K; kk += 4) {
            float p = 0.0f;
            #pragma unroll
            for (int i = 0; i < 7; i++) {
                int d = lane + 64 * i;
                if (d < D) p += tb[kk * D + d] * nv[i];
            }
            #pragma unroll
            for (int off = 32; off > 0; off >>= 1) p += __shfl_xor(p, off);
            if (lane == 0) ssc[kk] = p;
        }
        __syncthreads();

        float scores[K];
        #pragma unroll
        for (int kk = 0; kk < K; kk++) scores[kk] = ssc[kk];

        int mx_i = 0; float mx_v = scores[0];
        #pragma unroll
        for (int kk = 1; kk < K; kk++)
            if (scores[kk] > mx_v) { mx_v = scores[kk]; mx_i = kk; }

        bool any_nz = false; int nz_i = 0; float nz_v = -INFINITY;
        #pragma unroll
        for (int kk = 0; kk < K; kk++) {
            if (scores[kk] != 0.0f) {
                if (!any_nz || scores[kk] > nz_v) { nz_v = scores[kk]; nz_i = kk; }
                any_nz = true;
            }
        }

        bool hop = (mx_v == 0.0f) && !dead;
        int sel_i = (hop && any_nz) ? nz_i : mx_i;
        bool new_dead = dead || (hop && !any_nz);
        int nbr = nbrt[(size_t)idx * K + sel_i];
        int new_idx = (hop && any_nz) ? nbr : idx;

        float scale = new_dead ? 0.0f : valid;
        const float* selrow = tb + (size_t)sel_i * D;
        short* xr = xbase + (size_t)step * XP;
        for (int d = tid; d < XP; d += 256)
            xr[d] = (d < D) ? f2bf(selrow[d] * scale) : (short)0;

        idx = new_idx; dead = new_dead;
        __syncthreads();
    }
    for (int s = STEPS; s < SLOTS; s++) {
        short* xr = xbase + (size_t)s * XP;
        for (int d = tid; d < XP; d += 256) xr[d] = 0;
    }
}

// -------------------- Kernel 1b: weight transpose+concat to bf16 -------------
__global__ __launch_bounds__(256) void k_wconvT(
    const float* __restrict__ Wq, const float* __restrict__ Wk,
    const float* __restrict__ Wv, short* __restrict__ wT)
{
    int c = blockIdx.x;               // 0..1199
    int z = c / 400, n = c % 400;
    const float* W = (z == 0) ? Wq : (z == 1) ? Wk : Wv;
    for (int k = threadIdx.x; k < XP; k += 256)
        wT[(size_t)c * XP + k] = (k < 400) ? f2bf(W[(size_t)k * 400 + n]) : (short)0;
}

// -------------------- Kernel 2: fused QKV GEMM via bf16 MFMA ----------------
#define BM 128
#define BN 64
#define BKK 32

__global__ __launch_bounds__(256) void k_qkv_mfma(
    const short* __restrict__ xg,      // [8000][XP] bf16
    const short* __restrict__ wT,      // [1200][XP] bf16
    float* __restrict__ c)             // [8000][1200]
{
    __shared__ short xs[BM][BKK + 8];
    __shared__ short wt[BN][BKK + 8];

    int tid = threadIdx.x;
    int m0 = blockIdx.x * BM;
    int n0 = blockIdx.y * BN;
    int lane = tid & 63, w = tid >> 6;
    int wr = w >> 1, wc = w & 1;
    int quad = lane >> 4, l16 = lane & 15;

    floatx4 acc[4][2];
    #pragma unroll
    for (int i = 0; i < 4; i++)
        #pragma unroll
        for (int j = 0; j < 2; j++) acc[i][j] = (floatx4){0.f, 0.f, 0.f, 0.f};

    int xr = tid >> 1, xc = (tid & 1) * 16;
    int wrow = tid >> 2, wcol8 = (tid & 3) * 8;
    bool xok = (m0 + xr) < 8000;
    bool wok = (n0 + wrow) < NC;

    for (int k0 = 0; k0 < XP; k0 += BKK) {
        int4 xv0 = {0,0,0,0}, xv1 = {0,0,0,0}, wv = {0,0,0,0};
        if (xok) {
            const int4* src = (const int4*)(xg + (size_t)(m0 + xr) * XP + k0 + xc);
            xv0 = src[0]; xv1 = src[1];
        }
        if (wok)
            wv = *(const int4*)(wT + (size_t)(n0 + wrow) * XP + k0 + wcol8);
        __syncthreads();
        *(int4*)&xs[xr][xc]      = xv0;
        *(int4*)&xs[xr][xc + 8]  = xv1;
        *(int4*)&wt[wrow][wcol8] = wv;
        __syncthreads();

        short8 a[4], bf[2];
        #pragma unroll
        for (int fi = 0; fi < 4; fi++)
            a[fi] = *(const short8*)&xs[wr * 64 + fi * 16 + l16][quad * 8];
        #pragma unroll
        for (int fj = 0; fj < 2; fj++)
            bf[fj] = *(const short8*)&wt[wc * 32 + fj * 16 + l16][quad * 8];
        #pragma unroll
        for (int fi = 0; fi < 4; fi++)
            #pragma unroll
            for (int fj = 0; fj < 2; fj++)
                acc[fi][fj] = __builtin_amdgcn_mfma_f32_16x16x32_bf16(
                    a[fi], bf[fj], acc[fi][fj], 0, 0, 0);
    }

    #pragma unroll
    for (int fi = 0; fi < 4; fi++) {
        int grow_base = m0 + wr * 64 + fi * 16 + quad * 4;
        #pragma unroll
        for (int fj = 0; fj < 2; fj++) {
            int gcol = n0 + wc * 32 + fj * 16 + l16;
            #pragma unroll
            for (int r = 0; r < 4; r++) {
                int grow = grow_base + r;
                if (grow < 8000 && gcol < NC)
                    c[(size_t)grow * NC + gcol] = acc[fi][fj][r];
            }
        }
    }
}

// -------------------- Kernel 3: MFMA flash attention ------------------------
// One block (4 waves) per (b,h). K bf16 [512][24] in LDS (quad3 k-frag = zero
// regs), V^T bf16 [20 valid rows][520] with P-buffer + mask overlaid in the
// never-stored rows 20..31. Per wave: 8 q-tiles of 16 rows; flash over 16
// j-tiles of 32 keys; 4 MFMAs per (qt,jt). No barriers in the main loop.
#define KSTR 24
#define VSTR 520

__global__ __launch_bounds__(256) void k_attn3(
    const float* __restrict__ qkv,   // [8000][1200] = q|k|v
    const int* __restrict__ mask,    // [B,L]
    float* __restrict__ o)           // [8000][400]
{
    // Ksh: 512*24 shorts @0 ; VT: 32*520 shorts @12288 ; scratch inside VT rows 20..31
    __shared__ short sh[12288 + 32 * VSTR];   // 57856 B
    short* VTb = sh + 12288;
    short* Pb  = VTb + 20 * VSTR;             // Pbuf[4][16][40] shorts (16B-aligned)
    float* msk = (float*)(Pb + 4 * 16 * 40);  // [512]

    int b = blockIdx.x / H, h = blockIdx.x % H;
    int tid = threadIdx.x;
    int lane = tid & 63, w = tid >> 6;
    int quad = lane >> 4, l16 = lane & 15;
    const float scale = 0.22360679774997896f;  // 1/sqrt(20)

    // ---- stage K bf16 [512][24]: cols 20..23 zero, rows >=500 zero ----
    for (int i = tid; i < 512 * KSTR; i += 256) {
        int j = i / KSTR, d = i % KSTR;
        float v = (j < L && d < DH) ? qkv[(size_t)(b * L + j) * NC + 400 + h * DH + d] : 0.0f;
        sh[i] = f2bf(v);
    }
    // ---- stage V^T rows 0..19 (cols j) ----
    for (int i = tid; i < L * DH; i += 256) {
        int j = i / DH, d = i % DH;
        VTb[d * VSTR + j] = f2bf(qkv[(size_t)(b * L + j) * NC + 800 + h * DH + d]);
    }
    for (int i = tid; i < DH * 12; i += 256) {   // zero j-tail 500..511
        int d = i / 12, j = L + i % 12;
        VTb[d * VSTR + j] = 0;
    }
    for (int i = tid; i < 512; i += 256)
        msk[i] = (i < L && mask[(size_t)b * L + i] > 0) ? 1.0f : 0.0f;
    __syncthreads();

    short* Pw = Pb + w * 16 * 40;   // per-wave private P buffer [16][40]

    for (int qt = w; qt < 32; qt += 4) {
        // Q A-frag straight from global (scale folded in)
        int qrow = qt * 16 + l16;
        const float* qp = qkv + (size_t)(b * L + (qrow < L ? qrow : 0)) * NC + h * DH;
        short8 aq;
        #pragma unroll
        for (int jj = 0; jj < 8; jj++) {
            int k = quad * 8 + jj;
            float v = (qrow < L && k < DH) ? qp[k] * scale : 0.0f;
            aq[jj] = f2bf(v);
        }

        floatx4 O0 = (floatx4){0.f,0.f,0.f,0.f};
        floatx4 O1 = (floatx4){0.f,0.f,0.f,0.f};
        float mrun[4], lrun[4];
        #pragma unroll
        for (int r = 0; r < 4; r++) { mrun[r] = -INFINITY; lrun[r] = 0.0f; }

        for (int jt = 0; jt < 16; jt++) {
            // K B-frags (quad3 -> zero regs; quad<3 reads [quad*8..+8) of 24-col rows)
            short8 bk0 = (short8)(short)0, bk1 = (short8)(short)0;
            if (quad < 3) {
                bk0 = *(const short8*)&sh[(jt * 32 + l16) * KSTR + quad * 8];
                bk1 = *(const short8*)&sh[(jt * 32 + 16 + l16) * KSTR + quad * 8];
            }
            floatx4 z = (floatx4){0.f,0.f,0.f,0.f};
            floatx4 s0 = __builtin_amdgcn_mfma_f32_16x16x32_bf16(aq, bk0, z, 0, 0, 0);
            floatx4 s1 = __builtin_amdgcn_mfma_f32_16x16x32_bf16(aq, bk1, z, 0, 0, 0);

            float mk0 = msk[jt * 32 + l16];
            float mk1 = msk[jt * 32 + 16 + l16];
            #pragma unroll
            for (int r = 0; r < 4; r++) {
                s0[r] = (mk0 != 0.0f) ? s0[r] : -1e9f;
                s1[r] = (mk1 != 0.0f) ? s1[r] : -1e9f;
            }

            // row max across the 16 lanes of this quad
            float rmax[4];
            #pragma unroll
            for (int r = 0; r < 4; r++) rmax[r] = fmaxf(s0[r], s1[r]);
            #pragma unroll
            for (int st = 1; st < 16; st <<= 1)
                #pragma unroll
                for (int r = 0; r < 4; r++)
                    rmax[r] = fmaxf(rmax[r], __shfl_xor(rmax[r], st));

            float p0[4], p1[4], rsum[4];
            #pragma unroll
            for (int r = 0; r < 4; r++) {
                float mnew = fmaxf(mrun[r], rmax[r]);
                float alpha = __expf(mrun[r] - mnew);
                mrun[r] = mnew;
                lrun[r] *= alpha;
                O0[r] *= alpha; O1[r] *= alpha;
                p0[r] = __expf(s0[r] - mnew);
                p1[r] = __expf(s1[r] - mnew);
                rsum[r] = p0[r] + p1[r];
            }
            #pragma unroll
            for (int st = 1; st < 16; st <<= 1)
                #pragma unroll
                for (int r = 0; r < 4; r++)
                    rsum[r] += __shfl_xor(rsum[r], st);
            #pragma unroll
            for (int r = 0; r < 4; r++) lrun[r] += rsum[r];

            // P (C-layout) -> LDS -> A-layout, wave-private, no barrier
            #pragma unroll
            for (int r = 0; r < 4; r++) {
                Pw[(quad * 4 + r) * 40 + l16]      = f2bf(p0[r]);
                Pw[(quad * 4 + r) * 40 + 16 + l16] = f2bf(p1[r]);
            }
            short8 ap  = *(const short8*)&Pw[l16 * 40 + quad * 8];
            short8 bv0 = *(const short8*)&VTb[l16 * VSTR + jt * 32 + quad * 8];
            short8 bv1 = *(const short8*)&VTb[(16 + l16) * VSTR + jt * 32 + quad * 8];
            O0 = __builtin_amdgcn_mfma_f32_16x16x32_bf16(ap, bv0, O0, 0, 0, 0);
            O1 = __builtin_amdgcn_mfma_f32_16x16x32_bf16(ap, bv1, O1, 0, 0, 0);
        }

        #pragma unroll
        for (int r = 0; r < 4; r++) {
            int grow = qt * 16 + quad * 4 + r;
            if (grow < L) {
                float inv = 1.0f / lrun[r];
                float* op = o + (size_t)(b * L + grow) * (H * DH) + h * DH;
                op[l16] = O0[r] * inv;
                if (l16 < DH - 16) op[16 + l16] = O1[r] * inv;
            }
        }
    }
}

// -------------------- Kernel 4: LN1 + att_pool + LN2 ------------------------
__global__ __launch_bounds__(256) void k_pool(
    const float* __restrict__ o,
    const float* __restrict__ ln1g, const float* __restrict__ ln1b,
    const float* __restrict__ fc1w, const float* __restrict__ fc1b,
    const float* __restrict__ fc2w, const float* __restrict__ fc2b,
    const float* __restrict__ ln2g, const float* __restrict__ ln2b,
    const int* __restrict__ mask,   // [800,10]
    float* __restrict__ out)        // [800,400]
{
    __shared__ float xt[SLOTS][D];
    __shared__ float hv[SLOTS * ATT_H];
    __shared__ float es[SLOTS];
    __shared__ float red[8];

    int g = blockIdx.x;
    int tid = threadIdx.x;
    int lane = tid & 63, w = tid >> 6;

    const float* xg = o + (size_t)g * SLOTS * D;

    for (int s = w; s < SLOTS; s += 4) {
        const float* xr = xg + (size_t)s * D;
        float vbuf[7];
        float sum = 0.0f, sq = 0.0f;
        #pragma unroll
        for (int i = 0; i < 7; i++) {
            int d = lane + 64 * i;
            float v = (d < D) ? xr[d] : 0.0f;
            vbuf[i] = v; sum += v; sq += v * v;
        }
        #pragma unroll
        for (int off = 32; off > 0; off >>= 1) {
            sum += __shfl_xor(sum, off);
            sq  += __shfl_xor(sq, off);
        }
        float mean = sum / (float)D;
        float var = sq / (float)D - mean * mean;
        float rs = rsqrtf(var + EPS);
        #pragma unroll
        for (int i = 0; i < 7; i++) {
            int d = lane + 64 * i;
            if (d < D) xt[s][d] = (vbuf[i] - mean) * rs * ln1g[d] + ln1b[d];
        }
    }
    __syncthreads();

    {
        int jh = tid & 127;
        int s0 = tid >> 7;
        float hs[5];
        #pragma unroll
        for (int jj = 0; jj < 5; jj++) hs[jj] = fc1b[jh];
        for (int d = 0; d < D; d++) {
            float fw = fc1w[(size_t)d * ATT_H + jh];
            #pragma unroll
            for (int jj = 0; jj < 5; jj++) hs[jj] += xt[s0 + 2 * jj][d] * fw;
        }
        float f2 = fc2w[jh];
        #pragma unroll
        for (int jj = 0; jj < 5; jj++)
            hv[(s0 + 2 * jj) * ATT_H + jh] = tanhf(hs[jj]) * f2;
    }
    __syncthreads();

    for (int s = w; s < SLOTS; s += 4) {
        float p = hv[s * ATT_H + lane] + hv[s * ATT_H + lane + 64];
        #pragma unroll
        for (int off = 32; off > 0; off >>= 1) p += __shfl_xor(p, off);
        if (lane == 0) es[s] = p + fc2b[0];
    }
    __syncthreads();

    float ev[SLOTS];
    float emax = -INFINITY;
    #pragma unroll
    for (int s = 0; s < SLOTS; s++) {
        float e = (mask[(size_t)g * SLOTS + s] > 0) ? es[s] : -1e9f;
        ev[s] = e;
        if (e > emax) emax = e;
    }
    float esum = 0.0f;
    #pragma unroll
    for (int s = 0; s < SLOTS; s++) { ev[s] = __expf(ev[s] - emax); esum += ev[s]; }
    float einv = 1.0f / esum;

    int d0 = tid, d1 = tid + 256;
    float p0 = 0.0f, p1 = 0.0f;
    #pragma unroll
    for (int s = 0; s < SLOTS; s++) {
        p0 += ev[s] * xt[s][d0];
        if (d1 < D) p1 += ev[s] * xt[s][d1];
    }
    p0 *= einv; p1 *= einv;

    float sum = p0 + ((d1 < D) ? p1 : 0.0f);
    float sq  = p0 * p0 + ((d1 < D) ? p1 * p1 : 0.0f);
    #pragma unroll
    for (int off = 32; off > 0; off >>= 1) {
        sum += __shfl_xor(sum, off);
        sq  += __shfl_xor(sq, off);
    }
    if (lane == 0) { red[w] = sum; red[4 + w] = sq; }
    __syncthreads();
    float tsum = red[0] + red[1] + red[2] + red[3];
    float tsq  = red[4] + red[5] + red[6] + red[7];
    float mean = tsum / (float)D;
    float var = tsq / (float)D - mean * mean;
    float rs = rsqrtf(var + EPS);

    float* og = out + (size_t)g * D;
    og[d0] = (p0 - mean) * rs * ln2g[d0] + ln2b[d0];
    if (d1 < D) og[d1] = (p1 - mean) * rs * ln2g[d1] + ln2b[d1];
}

extern "C" void kernel_launch(void* const* d_in, const int* in_sizes, int n_in,
                              void* d_out, int out_size, void* d_ws, size_t ws_size,
                              hipStream_t stream) {
    const float* news  = (const float*)d_in[0];
    const float* table = (const float*)d_in[1];
    const float* Wq    = (const float*)d_in[2];
    const float* Wk    = (const float*)d_in[3];
    const float* Wv    = (const float*)d_in[4];
    const float* ln1g  = (const float*)d_in[5];
    const float* ln1b  = (const float*)d_in[6];
    const float* fc1w  = (const float*)d_in[7];
    const float* fc1b  = (const float*)d_in[8];
    const float* fc2w  = (const float*)d_in[9];
    const float* fc2b  = (const float*)d_in[10];
    const float* ln2g  = (const float*)d_in[11];
    const float* ln2b  = (const float*)d_in[12];
    const int* click   = (const int*)d_in[13];
    const int* nbrt    = (const int*)d_in[14];
    const int* mask    = (const int*)d_in[15];
    float* out = (float*)d_out;

    char* p = (char*)d_ws;
    short* xbf = (short*)p;  p += (size_t)8000 * XP * sizeof(short);   // 6.656 MB
    short* wT  = (short*)p;  p += (size_t)NC * XP * sizeof(short);     // 1.0 MB
    float* qkv = (float*)p;  p += (size_t)8000 * NC * sizeof(float);   // 38.4 MB
    float* ob  = (float*)p;                                            // 12.8 MB

    k_traverse<<<dim3(B * NN), dim3(256), 0, stream>>>(news, table, click, nbrt, xbf);
    k_wconvT<<<dim3(NC), dim3(256), 0, stream>>>(Wq, Wk, Wv, wT);
    k_qkv_mfma<<<dim3((8000 + BM - 1) / BM, (NC + BN - 1) / BN), dim3(256), 0, stream>>>(
        xbf, wT, qkv);
    k_attn3<<<dim3(B * H), dim3(256), 0, stream>>>(qkv, mask, ob);
    k_pool<<<dim3(B * NN), dim3(256), 0, stream>>>(ob, ln1g, ln1b, fc1w, fc1b, fc2w, fc2b,
                                                   ln2g, ln2b, mask, out);
}